// Round 1
// baseline (1038.273 us; speedup 1.0000x reference)
//
#include <hip/hip_runtime.h>
#include <hip/hip_bf16.h>
#include <type_traits>

#define B_SZ    2
#define S_LEN   2048
#define D_MODEL 2048
#define N_HEADS 16
#define D_HEAD  128
#define L_RANK  64
#define M_ROWS  (B_SZ * S_LEN)   // 4096

typedef short          bf16x8 __attribute__((ext_vector_type(8)));
typedef float          f32x4  __attribute__((ext_vector_type(4)));
typedef unsigned short us4v   __attribute__((ext_vector_type(4)));
typedef unsigned short us8v   __attribute__((ext_vector_type(8)));

static __device__ __forceinline__ unsigned short f2bf(float f) {
    unsigned int u = __float_as_uint(f);
    u += 0x7FFFu + ((u >> 16) & 1u);      // RNE; inputs are finite
    return (unsigned short)(u >> 16);
}

// ---------------------------------------------------------------------------
// W_eff[din, h*128+d] = sum_l Wl[din, h*64+l] * Wr[l, d];  b_eff analogous.
// grid (D/64, H, 2[k|v]), block 256
// ---------------------------------------------------------------------------
__global__ __launch_bounds__(256) void weff_kernel(
    const float* __restrict__ Wlk, const float* __restrict__ Wlv,
    const float* __restrict__ Wkr, const float* __restrict__ Wvr,
    const float* __restrict__ blk, const float* __restrict__ blv,
    const float* __restrict__ bkr, const float* __restrict__ bvr,
    float* __restrict__ Weffk, float* __restrict__ Weffv,
    float* __restrict__ beffk, float* __restrict__ beffv)
{
    const int z = blockIdx.z;
    const float* Wl = z ? Wlv : Wlk;
    const float* Wr = z ? Wvr : Wkr;
    const float* bl = z ? blv : blk;
    const float* br = z ? bvr : bkr;
    float* We = z ? Weffv : Weffk;
    float* be = z ? beffv : beffk;

    const int h = blockIdx.y;
    const int din0 = blockIdx.x * 64;
    const int tid = threadIdx.x;

    __shared__ float Wr_lds[L_RANK][D_HEAD];   // 32 KB
    __shared__ float Wl_lds[64][L_RANK];       // 16 KB

    #pragma unroll
    for (int c = 0; c < 8; ++c) {
        int e = c * 1024 + tid * 4;
        int l = e >> 7, d = e & 127;
        *(float4*)&Wr_lds[l][d] = *(const float4*)&Wr[l * D_HEAD + d];
    }
    #pragma unroll
    for (int c = 0; c < 4; ++c) {
        int e = c * 1024 + tid * 4;
        int r = e >> 6, l = e & 63;
        *(float4*)&Wl_lds[r][l] =
            *(const float4*)&Wl[(size_t)(din0 + r) * (L_RANK * N_HEADS) + h * L_RANK + l];
    }
    __syncthreads();

    for (int i = 0; i < 32; ++i) {
        int o = i * 256 + tid;
        int r = o >> 7, d = o & 127;
        float acc = 0.f;
        #pragma unroll
        for (int l = 0; l < L_RANK; ++l) acc += Wl_lds[r][l] * Wr_lds[l][d];
        We[(size_t)(din0 + r) * (N_HEADS * D_HEAD) + h * D_HEAD + d] = acc;
    }
    if (blockIdx.x == 0 && tid < D_HEAD) {
        float acc = br[tid];
        #pragma unroll
        for (int l = 0; l < L_RANK; ++l) acc += bl[h * L_RANK + l] * Wr_lds[l][tid];
        be[h * D_HEAD + tid] = acc;
    }
}

// ---------------------------------------------------------------------------
// C[M,N] = A[M,K] @ B[K,N] + bias.  A: fp32 or bf16(ushort). C: bf16 or fp32.
// 128x128 tile, BK=32, 4 waves each owning 64x64 (4x4 16x16x32 mfma frags).
// ---------------------------------------------------------------------------
template <typename AT, typename CT>
__global__ __launch_bounds__(256) void gemm_bias_kernel(
    const AT* __restrict__ A, const float* __restrict__ Bw,
    const float* __restrict__ bias, CT* __restrict__ C,
    int M, int N, int K)
{
    __shared__ unsigned short As[128][40];   // [row][k], +8 pad
    __shared__ unsigned short Bt[128][40];   // [col][k], +8 pad

    const int tid = threadIdx.x;
    const int lane = tid & 63, wid = tid >> 6;
    const int lr = lane & 15, lg = lane >> 4;
    const int wr = wid >> 1, wc = wid & 1;
    const int row0 = blockIdx.y * 128;
    const int col0 = blockIdx.x * 128;

    f32x4 acc[4][4];
    #pragma unroll
    for (int m = 0; m < 4; ++m)
        #pragma unroll
        for (int n = 0; n < 4; ++n) acc[m][n] = (f32x4){0.f, 0.f, 0.f, 0.f};

    for (int k0 = 0; k0 < K; k0 += 32) {
        __syncthreads();
        if constexpr (std::is_same<AT, float>::value) {
            #pragma unroll
            for (int c = 0; c < 4; ++c) {
                int e = c * 256 + tid;
                int r = e >> 3, c4 = (e & 7) << 2;
                const float4 v = *(const float4*)&A[(size_t)(row0 + r) * K + k0 + c4];
                us4v w = { f2bf(v.x), f2bf(v.y), f2bf(v.z), f2bf(v.w) };
                *(us4v*)&As[r][c4] = w;
            }
        } else {
            #pragma unroll
            for (int c = 0; c < 2; ++c) {
                int e = c * 256 + tid;
                int r = e >> 2, c8 = (e & 3) << 3;
                *(us8v*)&As[r][c8] = *(const us8v*)&A[(size_t)(row0 + r) * K + k0 + c8];
            }
        }
        #pragma unroll
        for (int c = 0; c < 4; ++c) {
            int e = c * 256 + tid;
            int kr = e >> 5, n4 = (e & 31) << 2;
            const float4 v = *(const float4*)&Bw[(size_t)(k0 + kr) * N + col0 + n4];
            Bt[n4 + 0][kr] = f2bf(v.x);
            Bt[n4 + 1][kr] = f2bf(v.y);
            Bt[n4 + 2][kr] = f2bf(v.z);
            Bt[n4 + 3][kr] = f2bf(v.w);
        }
        __syncthreads();

        bf16x8 af[4], bfr[4];
        #pragma unroll
        for (int m = 0; m < 4; ++m) af[m] = *(const bf16x8*)&As[wr * 64 + m * 16 + lr][lg * 8];
        #pragma unroll
        for (int n = 0; n < 4; ++n) bfr[n] = *(const bf16x8*)&Bt[wc * 64 + n * 16 + lr][lg * 8];
        #pragma unroll
        for (int m = 0; m < 4; ++m)
            #pragma unroll
            for (int n = 0; n < 4; ++n)
                acc[m][n] = __builtin_amdgcn_mfma_f32_16x16x32_bf16(af[m], bfr[n], acc[m][n], 0, 0, 0);
    }

    #pragma unroll
    for (int n = 0; n < 4; ++n) {
        const int col = col0 + wc * 64 + n * 16 + lr;
        const float bv = bias[col];
        #pragma unroll
        for (int m = 0; m < 4; ++m) {
            #pragma unroll
            for (int j = 0; j < 4; ++j) {
                const int row = row0 + wr * 64 + m * 16 + lg * 4 + j;
                float v = acc[m][n][j] + bv;
                if constexpr (std::is_same<CT, float>::value)
                    C[(size_t)row * N + col] = v;
                else
                    C[(size_t)row * N + col] = f2bf(v);
            }
        }
    }
}

// ---------------------------------------------------------------------------
// Causal flash attention. Q/K/V/O layouts: [b*S, h*128+d] bf16.
// Block: 128 q-rows for one (b,h); 4 waves x 32 rows; KVBLK=32.
// ---------------------------------------------------------------------------
__global__ __launch_bounds__(256) void flash_kernel(
    const unsigned short* __restrict__ Q,
    const unsigned short* __restrict__ Kg,
    const unsigned short* __restrict__ Vg,
    unsigned short* __restrict__ Og)
{
    __shared__ unsigned short K_lds[32][136];      // [k][d], +8 pad
    __shared__ unsigned short Vt_lds[128][40];     // [d][k], +8 pad
    __shared__ unsigned short P_lds[4][32][40];    // per-wave [q][k]

    const int tid = threadIdx.x;
    const int lane = tid & 63, wid = tid >> 6;
    const int lr = lane & 15, lg = lane >> 4;
    const int qt = blockIdx.x, h = blockIdx.y, b = blockIdx.z;
    const int q0 = qt * 128;
    const size_t base = (size_t)b * S_LEN * D_MODEL;
    const float scale = 0.08838834764831845f;   // 1/sqrt(128)

    // Q fragments in registers: wave rows [wid*32, wid*32+32)
    bf16x8 qf[2][4];
    #pragma unroll
    for (int m = 0; m < 2; ++m)
        #pragma unroll
        for (int kd = 0; kd < 4; ++kd)
            qf[m][kd] = *(const bf16x8*)&Q[base + (size_t)(q0 + wid * 32 + m * 16 + lr) * D_MODEL
                                           + h * D_HEAD + kd * 32 + lg * 8];

    f32x4 o_acc[2][8];
    #pragma unroll
    for (int m = 0; m < 2; ++m)
        #pragma unroll
        for (int f = 0; f < 8; ++f) o_acc[m][f] = (f32x4){0.f, 0.f, 0.f, 0.f};
    float mrow[2][4], lrow[2][4];
    #pragma unroll
    for (int m = 0; m < 2; ++m)
        #pragma unroll
        for (int r = 0; r < 4; ++r) { mrow[m][r] = -1e30f; lrow[m][r] = 0.f; }

    const int ntiles = (q0 + 128) / 32;
    for (int t = 0; t < ntiles; ++t) {
        const int kv0 = t * 32;
        __syncthreads();
        // stage K [32][128]
        #pragma unroll
        for (int c = 0; c < 2; ++c) {
            int e = c * 256 + tid;
            int r = e >> 4, c8 = (e & 15) << 3;
            *(us8v*)&K_lds[r][c8] =
                *(const us8v*)&Kg[base + (size_t)(kv0 + r) * D_MODEL + h * D_HEAD + c8];
        }
        // stage V transposed -> Vt[d][k]
        #pragma unroll
        for (int c = 0; c < 2; ++c) {
            int e = c * 256 + tid;
            int r = e >> 4, c8 = (e & 15) << 3;
            us8v vv = *(const us8v*)&Vg[base + (size_t)(kv0 + r) * D_MODEL + h * D_HEAD + c8];
            #pragma unroll
            for (int j = 0; j < 8; ++j) Vt_lds[c8 + j][r] = vv[j];
        }
        __syncthreads();

        // S = Q K^T
        f32x4 sacc[2][2];
        #pragma unroll
        for (int m = 0; m < 2; ++m)
            #pragma unroll
            for (int n = 0; n < 2; ++n) sacc[m][n] = (f32x4){0.f, 0.f, 0.f, 0.f};
        #pragma unroll
        for (int n = 0; n < 2; ++n)
            #pragma unroll
            for (int kd = 0; kd < 4; ++kd) {
                bf16x8 kf = *(const bf16x8*)&K_lds[n * 16 + lr][kd * 32 + lg * 8];
                #pragma unroll
                for (int m = 0; m < 2; ++m)
                    sacc[m][n] = __builtin_amdgcn_mfma_f32_16x16x32_bf16(qf[m][kd], kf, sacc[m][n], 0, 0, 0);
            }

        // online softmax (rows live in 16-lane groups; C layout row=(lg)*4+j, col=lr)
        #pragma unroll
        for (int m = 0; m < 2; ++m) {
            float sv[2][4];
            #pragma unroll
            for (int n = 0; n < 2; ++n)
                #pragma unroll
                for (int r = 0; r < 4; ++r) {
                    float v = sacc[m][n][r] * scale;
                    int ki = kv0 + n * 16 + lr;
                    int qi = q0 + wid * 32 + m * 16 + lg * 4 + r;
                    sv[n][r] = (ki > qi) ? -1e30f : v;
                }
            float alpha[4];
            #pragma unroll
            for (int r = 0; r < 4; ++r) {
                float mx = fmaxf(sv[0][r], sv[1][r]);
                #pragma unroll
                for (int off = 1; off < 16; off <<= 1) mx = fmaxf(mx, __shfl_xor(mx, off));
                float mnew = fmaxf(mrow[m][r], mx);
                alpha[r] = __expf(mrow[m][r] - mnew);
                float p0 = __expf(sv[0][r] - mnew);
                float p1 = __expf(sv[1][r] - mnew);
                P_lds[wid][m * 16 + lg * 4 + r][lr]      = f2bf(p0);
                P_lds[wid][m * 16 + lg * 4 + r][16 + lr] = f2bf(p1);
                float ps = p0 + p1;
                #pragma unroll
                for (int off = 1; off < 16; off <<= 1) ps += __shfl_xor(ps, off);
                lrow[m][r] = lrow[m][r] * alpha[r] + ps;
                mrow[m][r] = mnew;
            }
            #pragma unroll
            for (int f = 0; f < 8; ++f)
                #pragma unroll
                for (int r = 0; r < 4; ++r) o_acc[m][f][r] *= alpha[r];
        }
        __syncthreads();   // P_lds visibility (conservative)

        // O += P V
        #pragma unroll
        for (int m = 0; m < 2; ++m) {
            bf16x8 pf = *(const bf16x8*)&P_lds[wid][m * 16 + lr][lg * 8];
            #pragma unroll
            for (int f = 0; f < 8; ++f) {
                bf16x8 vf = *(const bf16x8*)&Vt_lds[f * 16 + lr][lg * 8];
                o_acc[m][f] = __builtin_amdgcn_mfma_f32_16x16x32_bf16(pf, vf, o_acc[m][f], 0, 0, 0);
            }
        }
    }

    #pragma unroll
    for (int m = 0; m < 2; ++m) {
        float inv[4];
        #pragma unroll
        for (int r = 0; r < 4; ++r) inv[r] = 1.0f / lrow[m][r];
        #pragma unroll
        for (int f = 0; f < 8; ++f)
            #pragma unroll
            for (int r = 0; r < 4; ++r) {
                int row = q0 + wid * 32 + m * 16 + lg * 4 + r;
                int col = h * D_HEAD + f * 16 + lr;
                Og[base + (size_t)row * D_MODEL + col] = f2bf(o_acc[m][f][r] * inv[r]);
            }
    }
}

// ---------------------------------------------------------------------------
extern "C" void kernel_launch(void* const* d_in, const int* in_sizes, int n_in,
                              void* d_out, int out_size, void* d_ws, size_t ws_size,
                              hipStream_t stream)
{
    const float* queries = (const float*)d_in[0];
    const float* keys    = (const float*)d_in[1];
    const float* values  = (const float*)d_in[2];
    const float* Wq  = (const float*)d_in[3];
    const float* bq  = (const float*)d_in[4];
    const float* Wlk = (const float*)d_in[5];
    const float* blk = (const float*)d_in[6];
    const float* Wlv = (const float*)d_in[7];
    const float* blv = (const float*)d_in[8];
    const float* Wkr = (const float*)d_in[9];
    const float* bkr = (const float*)d_in[10];
    const float* Wvr = (const float*)d_in[11];
    const float* bvr = (const float*)d_in[12];
    const float* Wo  = (const float*)d_in[13];
    const float* bo  = (const float*)d_in[14];
    float* out = (float*)d_out;

    char* ws = (char*)d_ws;
    const size_t SZ_BF = (size_t)M_ROWS * D_MODEL * 2;        // 16 MB
    const size_t SZ_WE = (size_t)D_MODEL * (N_HEADS * D_HEAD) * 4; // 16 MB
    unsigned short* q_bf  = (unsigned short*)(ws);
    unsigned short* k_bf  = (unsigned short*)(ws + SZ_BF);
    unsigned short* v_bf  = (unsigned short*)(ws + 2 * SZ_BF);
    unsigned short* ao_bf = (unsigned short*)(ws + 3 * SZ_BF);
    float* Weffk = (float*)(ws + 4 * SZ_BF);
    float* Weffv = (float*)(ws + 4 * SZ_BF + SZ_WE);
    float* beffk = (float*)(ws + 4 * SZ_BF + 2 * SZ_WE);
    float* beffv = beffk + N_HEADS * D_HEAD;

    weff_kernel<<<dim3(D_MODEL / 64, N_HEADS, 2), 256, 0, stream>>>(
        Wlk, Wlv, Wkr, Wvr, blk, blv, bkr, bvr, Weffk, Weffv, beffk, beffv);

    gemm_bias_kernel<float, unsigned short>
        <<<dim3(D_MODEL / 128, M_ROWS / 128), 256, 0, stream>>>(
            queries, Wq, bq, q_bf, M_ROWS, D_MODEL, D_MODEL);

    gemm_bias_kernel<float, unsigned short>
        <<<dim3(D_MODEL / 128, M_ROWS / 128), 256, 0, stream>>>(
            keys, Weffk, beffk, k_bf, M_ROWS, D_MODEL, D_MODEL);

    gemm_bias_kernel<float, unsigned short>
        <<<dim3(D_MODEL / 128, M_ROWS / 128), 256, 0, stream>>>(
            values, Weffv, beffv, v_bf, M_ROWS, D_MODEL, D_MODEL);

    flash_kernel<<<dim3(S_LEN / 128, N_HEADS, B_SZ), 256, 0, stream>>>(
        q_bf, k_bf, v_bf, ao_bf);

    gemm_bias_kernel<unsigned short, float>
        <<<dim3(D_MODEL / 128, M_ROWS / 128), 256, 0, stream>>>(
            ao_bf, Wo, bo, out, M_ROWS, D_MODEL, D_MODEL);
}

// Round 2
// 358.955 us; speedup vs baseline: 2.8925x; 2.8925x over previous
//
#include <hip/hip_runtime.h>
#include <hip/hip_bf16.h>

#define B_SZ    2
#define S_LEN   2048
#define D_MODEL 2048
#define N_HEADS 16
#define D_HEAD  128
#define L_RANK  64
#define M_ROWS  (B_SZ * S_LEN)   // 4096

typedef short          bf16x8 __attribute__((ext_vector_type(8)));
typedef float          f32x4  __attribute__((ext_vector_type(4)));
typedef unsigned short us4v   __attribute__((ext_vector_type(4)));
typedef unsigned short us8v   __attribute__((ext_vector_type(8)));

static __device__ __forceinline__ unsigned short f2bf(float f) {
    unsigned int u = __float_as_uint(f);
    u += 0x7FFFu + ((u >> 16) & 1u);      // RNE; inputs finite
    return (unsigned short)(u >> 16);
}

static __device__ __forceinline__ void gload16(const void* g, void* l) {
    __builtin_amdgcn_global_load_lds(
        (const __attribute__((address_space(1))) unsigned int*)g,
        (__attribute__((address_space(3))) unsigned int*)l, 16, 0, 0);
}

// ---------------------------------------------------------------------------
// fp32 -> bf16 elementwise (vectorized)
// ---------------------------------------------------------------------------
__global__ __launch_bounds__(256) void conv_bf16_kernel(
    const float* __restrict__ in, unsigned short* __restrict__ out)
{
    int i = (blockIdx.x * 256 + threadIdx.x) * 8;
    float4 a = *(const float4*)&in[i];
    float4 b = *(const float4*)&in[i + 4];
    us8v o = { f2bf(a.x), f2bf(a.y), f2bf(a.z), f2bf(a.w),
               f2bf(b.x), f2bf(b.y), f2bf(b.z), f2bf(b.w) };
    *(us8v*)&out[i] = o;
}

// ---------------------------------------------------------------------------
// W [K][N] fp32 -> WT [N][K] bf16 (Wq and Wo), 64x64 LDS tile transpose
// ---------------------------------------------------------------------------
__global__ __launch_bounds__(256) void transpose_w_kernel(
    const float* __restrict__ Wq, const float* __restrict__ Wo,
    unsigned short* __restrict__ WqT, unsigned short* __restrict__ WoT)
{
    const float* W = blockIdx.z ? Wo : Wq;
    unsigned short* WT = blockIdx.z ? WoT : WqT;
    const int k0 = blockIdx.y * 64, n0 = blockIdx.x * 64;
    const int tid = threadIdx.x;
    __shared__ float t[64][69];
    #pragma unroll
    for (int c = 0; c < 4; ++c) {
        int idx = c * 256 + tid;
        int r = idx >> 4, c4 = (idx & 15) * 4;
        float4 v = *(const float4*)&W[(size_t)(k0 + r) * D_MODEL + n0 + c4];
        t[r][c4] = v.x; t[r][c4 + 1] = v.y; t[r][c4 + 2] = v.z; t[r][c4 + 3] = v.w;
    }
    __syncthreads();
    #pragma unroll
    for (int c = 0; c < 2; ++c) {
        int idx = c * 256 + tid;
        int nr = idx >> 3, s = idx & 7;
        us8v o;
        #pragma unroll
        for (int j = 0; j < 8; ++j) o[j] = f2bf(t[s * 8 + j][nr]);
        *(us8v*)&WT[(size_t)(n0 + nr) * D_MODEL + k0 + s * 8] = o;
    }
}

// ---------------------------------------------------------------------------
// WeT[h*128+d][din] = sum_l Wl[din][h*64+l] * Wr[l][d]  (bf16, transposed out)
// beff[h*128+d] = br[d] + sum_l bl[h*64+l] * Wr[l][d]
// grid (32, 16, 2)
// ---------------------------------------------------------------------------
__global__ __launch_bounds__(256) void weff_t_kernel(
    const float* __restrict__ Wlk, const float* __restrict__ Wlv,
    const float* __restrict__ Wkr, const float* __restrict__ Wvr,
    const float* __restrict__ blk, const float* __restrict__ blv,
    const float* __restrict__ bkr, const float* __restrict__ bvr,
    unsigned short* __restrict__ WeTk, unsigned short* __restrict__ WeTv,
    float* __restrict__ beffk, float* __restrict__ beffv)
{
    const int z = blockIdx.z;
    const float* Wl = z ? Wlv : Wlk;
    const float* Wr = z ? Wvr : Wkr;
    const float* bl = z ? blv : blk;
    const float* br = z ? bvr : bkr;
    unsigned short* We = z ? WeTv : WeTk;
    float* be = z ? beffv : beffk;

    const int h = blockIdx.y;
    const int din0 = blockIdx.x * 64;
    const int tid = threadIdx.x;
    const int lane = tid & 63, w = tid >> 6;

    __shared__ float WrS[64][128];   // [l][d]
    __shared__ float WlT[64][65];    // [l][r]

    #pragma unroll
    for (int c = 0; c < 8; ++c) {
        int e = c * 1024 + tid * 4;
        int l = e >> 7, d = e & 127;
        *(float4*)&WrS[l][d] = *(const float4*)&Wr[l * D_HEAD + d];
    }
    #pragma unroll
    for (int c = 0; c < 4; ++c) {
        int idx = c * 256 + tid;
        int r = idx >> 4, l4 = (idx & 15) * 4;
        float4 v = *(const float4*)&Wl[(size_t)(din0 + r) * (L_RANK * N_HEADS) + h * L_RANK + l4];
        WlT[l4 + 0][r] = v.x; WlT[l4 + 1][r] = v.y; WlT[l4 + 2][r] = v.z; WlT[l4 + 3][r] = v.w;
    }
    __syncthreads();

    for (int i = 0; i < 32; ++i) {
        int d = i * 4 + w;
        float acc = 0.f;
        #pragma unroll
        for (int l = 0; l < L_RANK; ++l) acc += WlT[l][lane] * WrS[l][d];
        We[(size_t)(h * D_HEAD + d) * D_MODEL + din0 + lane] = f2bf(acc);
    }
    if (blockIdx.x == 0 && tid < D_HEAD) {
        float acc = br[tid];
        #pragma unroll
        for (int l = 0; l < L_RANK; ++l) acc += bl[h * L_RANK + l] * WrS[l][tid];
        be[h * D_HEAD + tid] = acc;
    }
}

// ---------------------------------------------------------------------------
// C = A[M,K]bf16 @ Bt[N,K]^T bf16 + bias.  128x128 tile, BK=32, m97-style
// global_load_lds staging with XOR chunk swizzle (conflict-free frag reads).
// MODE 0: C bf16 [M][N];  MODE 1: C fp32 [M][N];
// MODE 2: C bf16 written as v_t[(b*16+h)*128+d][s] (per-head transposed V).
// ---------------------------------------------------------------------------
template <int MODE>
__global__ __launch_bounds__(256) void gemm_bt_kernel(
    const unsigned short* __restrict__ A,
    const unsigned short* __restrict__ Bt,
    const float* __restrict__ bias,
    void* __restrict__ Cout,
    int M, int N, int K)
{
    __shared__ unsigned short Al[128 * 32];
    __shared__ unsigned short Bl[128 * 32];

    const int tid = threadIdx.x;
    const int lane = tid & 63, wid = tid >> 6;
    const int lr = lane & 15, lg = lane >> 4;
    const int wr = wid >> 1, wc = wid & 1;
    const int row0 = blockIdx.y * 128, col0 = blockIdx.x * 128;

    // staging: chunk idx -> (row = idx>>2, p = idx&3), stored chunk p holds
    // global chunk p ^ ((row>>1)&3)
    const unsigned short* ag[2];
    const unsigned short* bg[2];
    unsigned short* al[2];
    unsigned short* bl2[2];
    #pragma unroll
    for (int c = 0; c < 2; ++c) {
        int idx = wid * 128 + c * 64 + lane;
        int row = idx >> 2, p = idx & 3;
        int sp = p ^ ((row >> 1) & 3);
        ag[c]  = A  + (size_t)(row0 + row) * K + sp * 8;
        bg[c]  = Bt + (size_t)(col0 + row) * K + sp * 8;
        al[c]  = Al + idx * 8;
        bl2[c] = Bl + idx * 8;
    }
    const int sx = (lr >> 1) & 3;
    const int abase = (wr * 64 + lr) * 32 + ((lg ^ sx) * 8);
    const int bbase = (wc * 64 + lr) * 32 + ((lg ^ sx) * 8);

    f32x4 acc[4][4];
    #pragma unroll
    for (int m = 0; m < 4; ++m)
        #pragma unroll
        for (int n = 0; n < 4; ++n) acc[m][n] = (f32x4){0.f, 0.f, 0.f, 0.f};

    for (int k0 = 0; k0 < K; k0 += 32) {
        __syncthreads();
        #pragma unroll
        for (int c = 0; c < 2; ++c) { gload16(ag[c], al[c]); gload16(bg[c], bl2[c]); }
        #pragma unroll
        for (int c = 0; c < 2; ++c) { ag[c] += 32; bg[c] += 32; }
        __syncthreads();

        bf16x8 af[4], bfv[4];
        #pragma unroll
        for (int m = 0; m < 4; ++m) af[m]  = *(const bf16x8*)&Al[abase + m * 512];
        #pragma unroll
        for (int n = 0; n < 4; ++n) bfv[n] = *(const bf16x8*)&Bl[bbase + n * 512];
        __builtin_amdgcn_s_setprio(1);
        #pragma unroll
        for (int m = 0; m < 4; ++m)
            #pragma unroll
            for (int n = 0; n < 4; ++n)
                acc[m][n] = __builtin_amdgcn_mfma_f32_16x16x32_bf16(af[m], bfv[n], acc[m][n], 0, 0, 0);
        __builtin_amdgcn_s_setprio(0);
    }

    float bv[4];
    #pragma unroll
    for (int n = 0; n < 4; ++n) bv[n] = bias[col0 + wc * 64 + n * 16 + lr];

    #pragma unroll
    for (int m = 0; m < 4; ++m) {
        #pragma unroll
        for (int n = 0; n < 4; ++n) {
            const int col = col0 + wc * 64 + n * 16 + lr;
            const int rowb = row0 + wr * 64 + m * 16 + lg * 4;
            if constexpr (MODE == 0) {
                unsigned short* C = (unsigned short*)Cout;
                #pragma unroll
                for (int j = 0; j < 4; ++j)
                    C[(size_t)(rowb + j) * N + col] = f2bf(acc[m][n][j] + bv[n]);
            } else if constexpr (MODE == 1) {
                float* C = (float*)Cout;
                #pragma unroll
                for (int j = 0; j < 4; ++j)
                    C[(size_t)(rowb + j) * N + col] = acc[m][n][j] + bv[n];
            } else {
                unsigned short* Vt = (unsigned short*)Cout;
                const int bidx = rowb >> 11, s = rowb & 2047;
                const int h = col >> 7, d = col & 127;
                us4v o = { f2bf(acc[m][n][0] + bv[n]), f2bf(acc[m][n][1] + bv[n]),
                           f2bf(acc[m][n][2] + bv[n]), f2bf(acc[m][n][3] + bv[n]) };
                *(us4v*)&Vt[((size_t)(bidx * 16 + h) * 128 + d) * 2048 + s] = o;
            }
        }
    }
}

// ---------------------------------------------------------------------------
// Causal flash attention. QBLK=64 (4 waves x 16 rows), KVBLK=64, paired
// q-tiles (qt, 31-qt) for load balance; K/V double-buffered via gload_lds
// with XOR-swizzled sources; V consumed from per-head-transposed v_t.
// grid: 512 flat blocks, XCD-placed so each (b,h) stays on one XCD.
// ---------------------------------------------------------------------------
static __device__ __forceinline__ void flash_stage(
    const unsigned short* __restrict__ Kg, const unsigned short* __restrict__ Vt,
    unsigned short* Kl, unsigned short* Vl,
    size_t kg_off, size_t vt_off, int wid, int lane)
{
    #pragma unroll
    for (int c = 0; c < 4; ++c) {
        int idx = c * 64 + lane;
        int rl = idx >> 4, p = idx & 15;
        const unsigned short* g = Kg + kg_off + (size_t)(wid * 16 + rl) * D_MODEL + ((p ^ (rl & 7)) * 8);
        gload16(g, Kl + wid * 2048 + idx * 8);
    }
    #pragma unroll
    for (int c = 0; c < 4; ++c) {
        int idx = c * 64 + lane;
        int rl = idx >> 3, p = idx & 7;
        const unsigned short* g = Vt + vt_off + (size_t)(wid * 32 + rl) * S_LEN + ((p ^ (rl & 7)) * 8);
        gload16(g, Vl + wid * 2048 + idx * 8);
    }
}

__global__ __launch_bounds__(256) void flash_kernel(
    const unsigned short* __restrict__ Q,
    const unsigned short* __restrict__ Kg,
    const unsigned short* __restrict__ Vt,
    unsigned short* __restrict__ Og)
{
    __shared__ unsigned short Klds[2][64 * 128];
    __shared__ unsigned short Vlds[2][128 * 64];
    __shared__ unsigned short Plds[4][16][72];

    const int tid = threadIdx.x;
    const int lane = tid & 63, wid = tid >> 6;
    const int lr = lane & 15, lg = lane >> 4;

    // flat = (pair*4 + bh_hi)*8 + (bh&7): all blocks of one (b,h) on one XCD
    const int flat = blockIdx.x;
    const int pair = flat >> 5;
    const int bh = ((flat >> 3) & 3) * 8 + (flat & 7);
    const int b = bh >> 4, h = bh & 15;
    const size_t base = (size_t)b * S_LEN * D_MODEL;
    const float scale = 0.08838834764831845f;   // 1/sqrt(128)

    const int kxor = lr & 7;
    int kbase[4], vbase[2];
    #pragma unroll
    for (int kd = 0; kd < 4; ++kd) kbase[kd] = lr * 128 + (((kd * 4 + lg) ^ kxor) * 8);
    #pragma unroll
    for (int kk = 0; kk < 2; ++kk) vbase[kk] = lr * 64 + (((kk * 4 + lg) ^ kxor) * 8);
    const int pbase = (wid * 16 + lr) * 72 + lg * 8;

    #pragma unroll 1
    for (int ph = 0; ph < 2; ++ph) {
        const int qt = ph ? (31 - pair) : pair;
        const int q0 = qt * 64;
        const int nt = qt + 1;

        bf16x8 qf[4];
        #pragma unroll
        for (int kd = 0; kd < 4; ++kd)
            qf[kd] = *(const bf16x8*)&Q[base + (size_t)(q0 + wid * 16 + lr) * D_MODEL
                                        + h * D_HEAD + kd * 32 + lg * 8];

        f32x4 o_acc[8];
        #pragma unroll
        for (int f = 0; f < 8; ++f) o_acc[f] = (f32x4){0.f, 0.f, 0.f, 0.f};
        float m_r[4], l_r[4];
        #pragma unroll
        for (int r = 0; r < 4; ++r) { m_r[r] = -1e30f; l_r[r] = 0.f; }

        __syncthreads();
        flash_stage(Kg, Vt, Klds[0], Vlds[0],
                    base + h * D_HEAD, (size_t)bh * 128 * 2048, wid, lane);

        #pragma unroll 1
        for (int t = 0; t < nt; ++t) {
            const int bb = t & 1;
            __syncthreads();   // compiler drains vmcnt here -> buf[bb] ready
            if (t + 1 < nt)
                flash_stage(Kg, Vt, Klds[bb ^ 1], Vlds[bb ^ 1],
                            base + (size_t)(t + 1) * 64 * D_MODEL + h * D_HEAD,
                            (size_t)bh * 128 * 2048 + (t + 1) * 64, wid, lane);

            // S = Q K^T
            f32x4 sacc[4];
            #pragma unroll
            for (int n = 0; n < 4; ++n) sacc[n] = (f32x4){0.f, 0.f, 0.f, 0.f};
            __builtin_amdgcn_s_setprio(1);
            #pragma unroll
            for (int n = 0; n < 4; ++n)
                #pragma unroll
                for (int kd = 0; kd < 4; ++kd) {
                    bf16x8 kf = *(const bf16x8*)&Klds[bb][kbase[kd] + n * 2048];
                    sacc[n] = __builtin_amdgcn_mfma_f32_16x16x32_bf16(qf[kd], kf, sacc[n], 0, 0, 0);
                }
            __builtin_amdgcn_s_setprio(0);

            // online softmax; S row = lg*4+r, col = n*16+lr
            const bool diag = (t == qt);
            float alpha[4];
            #pragma unroll
            for (int r = 0; r < 4; ++r) {
                float sv[4];
                #pragma unroll
                for (int n = 0; n < 4; ++n) {
                    float v = sacc[n][r] * scale;
                    if (diag && (n * 16 + lr > wid * 16 + lg * 4 + r)) v = -1e30f;
                    sv[n] = v;
                }
                float mx = fmaxf(fmaxf(sv[0], sv[1]), fmaxf(sv[2], sv[3]));
                #pragma unroll
                for (int off = 8; off >= 1; off >>= 1) mx = fmaxf(mx, __shfl_xor(mx, off));
                float mnew = fmaxf(m_r[r], mx);
                alpha[r] = __expf(m_r[r] - mnew);
                float ps = 0.f;
                #pragma unroll
                for (int n = 0; n < 4; ++n) {
                    float p = __expf(sv[n] - mnew);
                    ps += p;
                    Plds[wid][lg * 4 + r][n * 16 + lr] = f2bf(p);
                }
                #pragma unroll
                for (int off = 8; off >= 1; off >>= 1) ps += __shfl_xor(ps, off);
                l_r[r] = l_r[r] * alpha[r] + ps;
                m_r[r] = mnew;
            }
            #pragma unroll
            for (int f = 0; f < 8; ++f)
                #pragma unroll
                for (int r = 0; r < 4; ++r) o_acc[f][r] *= alpha[r];

            // O += P V
            bf16x8 pf[2];
            #pragma unroll
            for (int kk = 0; kk < 2; ++kk)
                pf[kk] = *(const bf16x8*)&((const unsigned short*)Plds)[pbase + kk * 32];
            __builtin_amdgcn_s_setprio(1);
            #pragma unroll
            for (int f = 0; f < 8; ++f)
                #pragma unroll
                for (int kk = 0; kk < 2; ++kk) {
                    bf16x8 vf = *(const bf16x8*)&Vlds[bb][vbase[kk] + f * 1024];
                    o_acc[f] = __builtin_amdgcn_mfma_f32_16x16x32_bf16(pf[kk], vf, o_acc[f], 0, 0, 0);
                }
            __builtin_amdgcn_s_setprio(0);
        }

        #pragma unroll
        for (int r = 0; r < 4; ++r) {
            float inv = 1.0f / l_r[r];
            size_t rowoff = base + (size_t)(q0 + wid * 16 + lg * 4 + r) * D_MODEL + h * D_HEAD + lr;
            #pragma unroll
            for (int f = 0; f < 8; ++f)
                Og[rowoff + f * 16] = f2bf(o_acc[f][r] * inv);
        }
    }
}

// ---------------------------------------------------------------------------
extern "C" void kernel_launch(void* const* d_in, const int* in_sizes, int n_in,
                              void* d_out, int out_size, void* d_ws, size_t ws_size,
                              hipStream_t stream)
{
    const float* queries = (const float*)d_in[0];
    const float* keys    = (const float*)d_in[1];
    const float* values  = (const float*)d_in[2];
    const float* Wq  = (const float*)d_in[3];
    const float* bq  = (const float*)d_in[4];
    const float* Wlk = (const float*)d_in[5];
    const float* blk = (const float*)d_in[6];
    const float* Wlv = (const float*)d_in[7];
    const float* blv = (const float*)d_in[8];
    const float* Wkr = (const float*)d_in[9];
    const float* bkr = (const float*)d_in[10];
    const float* Wvr = (const float*)d_in[11];
    const float* bvr = (const float*)d_in[12];
    const float* Wo  = (const float*)d_in[13];
    const float* bo  = (const float*)d_in[14];
    float* out = (float*)d_out;

    char* ws = (char*)d_ws;
    const size_t MB16 = (size_t)M_ROWS * D_MODEL * 2;       // 16 MB
    const size_t MB8  = (size_t)D_MODEL * D_MODEL * 2;      // 8 MB
    unsigned short* abf  = (unsigned short*)(ws);                 // reused; also ao
    unsigned short* q_bf = (unsigned short*)(ws + MB16);
    unsigned short* k_bf = (unsigned short*)(ws + 2 * MB16);
    unsigned short* v_t  = (unsigned short*)(ws + 3 * MB16);
    unsigned short* WqT  = (unsigned short*)(ws + 4 * MB16);
    unsigned short* WeTk = (unsigned short*)(ws + 4 * MB16 + MB8);
    unsigned short* WeTv = (unsigned short*)(ws + 4 * MB16 + 2 * MB8);
    unsigned short* WoT  = (unsigned short*)(ws + 4 * MB16 + 3 * MB8);
    float* beffk = (float*)(ws + 4 * MB16 + 4 * MB8);
    float* beffv = beffk + D_MODEL;

    const int nconv = (M_ROWS * D_MODEL) / 2048;   // 4096 blocks

    weff_t_kernel<<<dim3(32, 16, 2), 256, 0, stream>>>(
        Wlk, Wlv, Wkr, Wvr, blk, blv, bkr, bvr, WeTk, WeTv, beffk, beffv);
    transpose_w_kernel<<<dim3(32, 32, 2), 256, 0, stream>>>(Wq, Wo, WqT, WoT);

    conv_bf16_kernel<<<nconv, 256, 0, stream>>>(queries, abf);
    gemm_bt_kernel<0><<<dim3(16, 32), 256, 0, stream>>>(
        abf, WqT, bq, q_bf, M_ROWS, D_MODEL, D_MODEL);

    conv_bf16_kernel<<<nconv, 256, 0, stream>>>(keys, abf);
    gemm_bt_kernel<0><<<dim3(16, 32), 256, 0, stream>>>(
        abf, WeTk, beffk, k_bf, M_ROWS, D_MODEL, D_MODEL);

    conv_bf16_kernel<<<nconv, 256, 0, stream>>>(values, abf);
    gemm_bt_kernel<2><<<dim3(16, 32), 256, 0, stream>>>(
        abf, WeTv, beffv, v_t, M_ROWS, D_MODEL, D_MODEL);

    flash_kernel<<<512, 256, 0, stream>>>(q_bf, k_bf, v_t, abf);

    gemm_bt_kernel<1><<<dim3(16, 32), 256, 0, stream>>>(
        abf, WoT, bo, out, M_ROWS, D_MODEL, D_MODEL);
}

// Round 3
// 340.746 us; speedup vs baseline: 3.0471x; 1.0534x over previous
//
#include <hip/hip_runtime.h>
#include <hip/hip_bf16.h>

#define B_SZ    2
#define S_LEN   2048
#define D_MODEL 2048
#define N_HEADS 16
#define D_HEAD  128
#define L_RANK  64
#define M_ROWS  (B_SZ * S_LEN)   // 4096

typedef short          bf16x8 __attribute__((ext_vector_type(8)));
typedef float          f32x4  __attribute__((ext_vector_type(4)));
typedef float          f32x16 __attribute__((ext_vector_type(16)));
typedef unsigned short us4v   __attribute__((ext_vector_type(4)));
typedef unsigned short us8v   __attribute__((ext_vector_type(8)));
typedef unsigned int   u32x4  __attribute__((ext_vector_type(4)));

// log2(e) / sqrt(128), folded into the Q projection epilogue
#define SCALE_Q 0.127517432f

static __device__ __forceinline__ unsigned short f2bf(float f) {
    unsigned int u = __float_as_uint(f);
    u += 0x7FFFu + ((u >> 16) & 1u);      // RNE; inputs finite
    return (unsigned short)(u >> 16);
}

static __device__ __forceinline__ void gload16(const void* g, void* l) {
    __builtin_amdgcn_global_load_lds(
        (const __attribute__((address_space(1))) unsigned int*)g,
        (__attribute__((address_space(3))) unsigned int*)l, 16, 0, 0);
}

static __device__ __forceinline__ float exp2_hw(float x) {
    float r; asm("v_exp_f32 %0, %1" : "=v"(r) : "v"(x)); return r;
}
static __device__ __forceinline__ unsigned int cvtpk_bf16(float a, float b) {
    unsigned int r; asm("v_cvt_pk_bf16_f32 %0, %1, %2" : "=v"(r) : "v"(a), "v"(b)); return r;
}

// ---------------------------------------------------------------------------
// fp32 -> bf16 elementwise (vectorized)
// ---------------------------------------------------------------------------
__global__ __launch_bounds__(256) void conv_bf16_kernel(
    const float* __restrict__ in, unsigned short* __restrict__ out)
{
    int i = (blockIdx.x * 256 + threadIdx.x) * 8;
    float4 a = *(const float4*)&in[i];
    float4 b = *(const float4*)&in[i + 4];
    us8v o = { f2bf(a.x), f2bf(a.y), f2bf(a.z), f2bf(a.w),
               f2bf(b.x), f2bf(b.y), f2bf(b.z), f2bf(b.w) };
    *(us8v*)&out[i] = o;
}

// ---------------------------------------------------------------------------
// W [K][N] fp32 -> WT [N][K] bf16 (Wq and Wo), 64x64 LDS tile transpose
// ---------------------------------------------------------------------------
__global__ __launch_bounds__(256) void transpose_w_kernel(
    const float* __restrict__ Wq, const float* __restrict__ Wo,
    unsigned short* __restrict__ WqT, unsigned short* __restrict__ WoT)
{
    const float* W = blockIdx.z ? Wo : Wq;
    unsigned short* WT = blockIdx.z ? WoT : WqT;
    const int k0 = blockIdx.y * 64, n0 = blockIdx.x * 64;
    const int tid = threadIdx.x;
    __shared__ float t[64][69];
    #pragma unroll
    for (int c = 0; c < 4; ++c) {
        int idx = c * 256 + tid;
        int r = idx >> 4, c4 = (idx & 15) * 4;
        float4 v = *(const float4*)&W[(size_t)(k0 + r) * D_MODEL + n0 + c4];
        t[r][c4] = v.x; t[r][c4 + 1] = v.y; t[r][c4 + 2] = v.z; t[r][c4 + 3] = v.w;
    }
    __syncthreads();
    #pragma unroll
    for (int c = 0; c < 2; ++c) {
        int idx = c * 256 + tid;
        int nr = idx >> 3, s = idx & 7;
        us8v o;
        #pragma unroll
        for (int j = 0; j < 8; ++j) o[j] = f2bf(t[s * 8 + j][nr]);
        *(us8v*)&WT[(size_t)(n0 + nr) * D_MODEL + k0 + s * 8] = o;
    }
}

// ---------------------------------------------------------------------------
// WeT[h*128+d][din] = sum_l Wl[din][h*64+l] * Wr[l][d]  (bf16, transposed out)
// ---------------------------------------------------------------------------
__global__ __launch_bounds__(256) void weff_t_kernel(
    const float* __restrict__ Wlk, const float* __restrict__ Wlv,
    const float* __restrict__ Wkr, const float* __restrict__ Wvr,
    const float* __restrict__ blk, const float* __restrict__ blv,
    const float* __restrict__ bkr, const float* __restrict__ bvr,
    unsigned short* __restrict__ WeTk, unsigned short* __restrict__ WeTv,
    float* __restrict__ beffk, float* __restrict__ beffv)
{
    const int z = blockIdx.z;
    const float* Wl = z ? Wlv : Wlk;
    const float* Wr = z ? Wvr : Wkr;
    const float* bl = z ? blv : blk;
    const float* br = z ? bvr : bkr;
    unsigned short* We = z ? WeTv : WeTk;
    float* be = z ? beffv : beffk;

    const int h = blockIdx.y;
    const int din0 = blockIdx.x * 64;
    const int tid = threadIdx.x;
    const int lane = tid & 63, w = tid >> 6;

    __shared__ float WrS[64][128];   // [l][d]
    __shared__ float WlT[64][65];    // [l][r]

    #pragma unroll
    for (int c = 0; c < 8; ++c) {
        int e = c * 1024 + tid * 4;
        int l = e >> 7, d = e & 127;
        *(float4*)&WrS[l][d] = *(const float4*)&Wr[l * D_HEAD + d];
    }
    #pragma unroll
    for (int c = 0; c < 4; ++c) {
        int idx = c * 256 + tid;
        int r = idx >> 4, l4 = (idx & 15) * 4;
        float4 v = *(const float4*)&Wl[(size_t)(din0 + r) * (L_RANK * N_HEADS) + h * L_RANK + l4];
        WlT[l4 + 0][r] = v.x; WlT[l4 + 1][r] = v.y; WlT[l4 + 2][r] = v.z; WlT[l4 + 3][r] = v.w;
    }
    __syncthreads();

    for (int i = 0; i < 32; ++i) {
        int d = i * 4 + w;
        float acc = 0.f;
        #pragma unroll
        for (int l = 0; l < L_RANK; ++l) acc += WlT[l][lane] * WrS[l][d];
        We[(size_t)(h * D_HEAD + d) * D_MODEL + din0 + lane] = f2bf(acc);
    }
    if (blockIdx.x == 0 && tid < D_HEAD) {
        float acc = br[tid];
        #pragma unroll
        for (int l = 0; l < L_RANK; ++l) acc += bl[h * L_RANK + l] * WrS[l][tid];
        be[h * D_HEAD + tid] = acc;
    }
}

// ---------------------------------------------------------------------------
// C = A[M,K]bf16 @ Bt[N,K]^T bf16 + bias, * omul.  128x128 tile, BK=32.
// MODE 0: C bf16; MODE 1: C fp32; MODE 2: C bf16 as v_t[(b*16+h)*128+d][s].
// ---------------------------------------------------------------------------
template <int MODE>
__global__ __launch_bounds__(256) void gemm_bt_kernel(
    const unsigned short* __restrict__ A,
    const unsigned short* __restrict__ Bt,
    const float* __restrict__ bias,
    void* __restrict__ Cout,
    int M, int N, int K, float omul)
{
    __shared__ unsigned short Al[128 * 32];
    __shared__ unsigned short Bl[128 * 32];

    const int tid = threadIdx.x;
    const int lane = tid & 63, wid = tid >> 6;
    const int lr = lane & 15, lg = lane >> 4;
    const int wr = wid >> 1, wc = wid & 1;
    const int row0 = blockIdx.y * 128, col0 = blockIdx.x * 128;

    const unsigned short* ag[2];
    const unsigned short* bg[2];
    unsigned short* al[2];
    unsigned short* bl2[2];
    #pragma unroll
    for (int c = 0; c < 2; ++c) {
        int idx = wid * 128 + c * 64 + lane;
        int row = idx >> 2, p = idx & 3;
        int sp = p ^ ((row >> 1) & 3);
        ag[c]  = A  + (size_t)(row0 + row) * K + sp * 8;
        bg[c]  = Bt + (size_t)(col0 + row) * K + sp * 8;
        al[c]  = Al + idx * 8;
        bl2[c] = Bl + idx * 8;
    }
    const int sx = (lr >> 1) & 3;
    const int abase = (wr * 64 + lr) * 32 + ((lg ^ sx) * 8);
    const int bbase = (wc * 64 + lr) * 32 + ((lg ^ sx) * 8);

    f32x4 acc[4][4];
    #pragma unroll
    for (int m = 0; m < 4; ++m)
        #pragma unroll
        for (int n = 0; n < 4; ++n) acc[m][n] = (f32x4){0.f, 0.f, 0.f, 0.f};

    for (int k0 = 0; k0 < K; k0 += 32) {
        __syncthreads();
        #pragma unroll
        for (int c = 0; c < 2; ++c) { gload16(ag[c], al[c]); gload16(bg[c], bl2[c]); }
        #pragma unroll
        for (int c = 0; c < 2; ++c) { ag[c] += 32; bg[c] += 32; }
        __syncthreads();

        bf16x8 af[4], bfv[4];
        #pragma unroll
        for (int m = 0; m < 4; ++m) af[m]  = *(const bf16x8*)&Al[abase + m * 512];
        #pragma unroll
        for (int n = 0; n < 4; ++n) bfv[n] = *(const bf16x8*)&Bl[bbase + n * 512];
        __builtin_amdgcn_s_setprio(1);
        #pragma unroll
        for (int m = 0; m < 4; ++m)
            #pragma unroll
            for (int n = 0; n < 4; ++n)
                acc[m][n] = __builtin_amdgcn_mfma_f32_16x16x32_bf16(af[m], bfv[n], acc[m][n], 0, 0, 0);
        __builtin_amdgcn_s_setprio(0);
    }

    float bv[4];
    #pragma unroll
    for (int n = 0; n < 4; ++n) bv[n] = bias[col0 + wc * 64 + n * 16 + lr];

    #pragma unroll
    for (int m = 0; m < 4; ++m) {
        #pragma unroll
        for (int n = 0; n < 4; ++n) {
            const int col = col0 + wc * 64 + n * 16 + lr;
            const int rowb = row0 + wr * 64 + m * 16 + lg * 4;
            if constexpr (MODE == 0) {
                unsigned short* C = (unsigned short*)Cout;
                #pragma unroll
                for (int j = 0; j < 4; ++j)
                    C[(size_t)(rowb + j) * N + col] = f2bf((acc[m][n][j] + bv[n]) * omul);
            } else if constexpr (MODE == 1) {
                float* C = (float*)Cout;
                #pragma unroll
                for (int j = 0; j < 4; ++j)
                    C[(size_t)(rowb + j) * N + col] = (acc[m][n][j] + bv[n]) * omul;
            } else {
                unsigned short* Vt = (unsigned short*)Cout;
                const int bidx = rowb >> 11, s = rowb & 2047;
                const int h = col >> 7, d = col & 127;
                us4v o = { f2bf(acc[m][n][0] + bv[n]), f2bf(acc[m][n][1] + bv[n]),
                           f2bf(acc[m][n][2] + bv[n]), f2bf(acc[m][n][3] + bv[n]) };
                *(us4v*)&Vt[((size_t)(bidx * 16 + h) * 128 + d) * 2048 + s] = o;
            }
        }
    }
}

// ---------------------------------------------------------------------------
// Causal flash attention, swapped-QK 32x32x16 structure.
// Block: 4 waves x 32 q-rows = 128 q-rows of one (b,h). KVBLK=64, dbuf LDS.
// Q pre-scaled by log2(e)/sqrt(128); softmax in exp2 domain, in-register.
// Balanced grid: 512 blocks; b<256 -> qt=b>>5, b>=256 -> qt=23-(b>>5) so each
// CU's two resident blocks sum to constant work; bh in low 5 bits for XCD/L2.
// ---------------------------------------------------------------------------
static __device__ __forceinline__ void flash_stage(
    const unsigned short* __restrict__ kgh,   // K base for (b, col h*128), row stride 2048
    const unsigned short* __restrict__ vtb,   // V^T base for bh, row stride 2048
    unsigned short* Kl, unsigned short* Vl, int kv0, int tid)
{
    #pragma unroll
    for (int c = 0; c < 4; ++c) {
        int idx = c * 256 + tid;
        int r = idx >> 4, ch = idx & 15;
        gload16(kgh + (size_t)(kv0 + r) * D_MODEL + ((ch ^ (r & 7)) * 8), Kl + idx * 8);
    }
    #pragma unroll
    for (int c = 0; c < 4; ++c) {
        int idx = c * 256 + tid;
        int d = idx >> 3, ch = idx & 7;
        gload16(vtb + (size_t)d * S_LEN + kv0 + ((ch ^ (d & 7)) * 8), Vl + idx * 8);
    }
}

__global__ __launch_bounds__(256, 2) void flash_kernel(
    const unsigned short* __restrict__ Q,
    const unsigned short* __restrict__ Kg,
    const unsigned short* __restrict__ Vt,
    unsigned short* __restrict__ Og)
{
    __shared__ unsigned short Klds[2][64 * 128];
    __shared__ unsigned short Vlds[2][128 * 64];

    const int tid = threadIdx.x;
    const int lane = tid & 63, wid = tid >> 6;
    const int lc = lane & 31, hi = lane >> 5;

    const int blk = blockIdx.x;
    const int jj = blk >> 5;
    const int qt = (jj < 8) ? jj : 23 - jj;
    const int bh = blk & 31;
    const int b = bh >> 4, h = bh & 15;
    const size_t base = (size_t)b * S_LEN * D_MODEL;
    const unsigned short* kgh = Kg + base + h * D_HEAD;
    const unsigned short* vtb = Vt + (size_t)bh * D_HEAD * S_LEN;

    const int q0w = qt * 128 + wid * 32;
    const int qcol = q0w + lc;

    // Q fragments (B-operand): qf[dc] = Q[qcol][dc*16 + hi*8 .. +8]
    bf16x8 qf[8];
    #pragma unroll
    for (int dc = 0; dc < 8; ++dc)
        qf[dc] = *(const bf16x8*)&Q[base + (size_t)qcol * D_MODEL + h * D_HEAD + dc * 16 + hi * 8];

    f32x16 o_acc[4];
    #pragma unroll
    for (int dt = 0; dt < 4; ++dt)
        #pragma unroll
        for (int r = 0; r < 16; ++r) o_acc[dt][r] = 0.f;
    float m_r = -3e38f, l_r = 0.f;

    const int kxor = lc & 7;
    const int nt = 2 * qt + 2;

    flash_stage(kgh, vtb, Klds[0], Vlds[0], 0, tid);

    #pragma unroll 1
    for (int t = 0; t < nt; ++t) {
        const int bb = t & 1;
        const int kv0 = t * 64;
        __syncthreads();   // drains staging vmcnt; buf bb ready, bb^1 free
        if (t + 1 < nt)
            flash_stage(kgh, vtb, Klds[bb ^ 1], Vlds[bb ^ 1], (t + 1) * 64, tid);

        // ---- S^T = K Q^T  (two 32x32 tiles over k) ----
        f32x16 s0, s1;
        #pragma unroll
        for (int r = 0; r < 16; ++r) { s0[r] = 0.f; s1[r] = 0.f; }
        __builtin_amdgcn_s_setprio(1);
        #pragma unroll
        for (int dc = 0; dc < 8; ++dc) {
            bf16x8 kf = *(const bf16x8*)&Klds[bb][lc * 128 + (((dc * 2 + hi) ^ kxor) * 8)];
            s0 = __builtin_amdgcn_mfma_f32_32x32x16_bf16(kf, qf[dc], s0, 0, 0, 0);
        }
        #pragma unroll
        for (int dc = 0; dc < 8; ++dc) {
            bf16x8 kf = *(const bf16x8*)&Klds[bb][(32 + lc) * 128 + (((dc * 2 + hi) ^ kxor) * 8)];
            s1 = __builtin_amdgcn_mfma_f32_32x32x16_bf16(kf, qf[dc], s1, 0, 0, 0);
        }
        __builtin_amdgcn_s_setprio(0);

        // ---- causal mask (last two tiles only) ----
        if (t >= nt - 2) {
            #pragma unroll
            for (int r = 0; r < 16; ++r) {
                int krow = (r & 3) + 8 * (r >> 2) + 4 * hi;
                if (kv0 + krow > qcol)      s0[r] = -3e38f;
                if (kv0 + 32 + krow > qcol) s1[r] = -3e38f;
            }
        }

        // ---- online softmax (exp2 domain), fully in-register ----
        float mt[8];
        #pragma unroll
        for (int i = 0; i < 8; ++i)
            mt[i] = fmaxf(fmaxf(s0[2 * i], s0[2 * i + 1]), fmaxf(s1[2 * i], s1[2 * i + 1]));
        float mA = fmaxf(fmaxf(mt[0], mt[1]), fmaxf(mt[2], mt[3]));
        float mB = fmaxf(fmaxf(mt[4], mt[5]), fmaxf(mt[6], mt[7]));
        float sm = fmaxf(mA, mB);
        sm = fmaxf(sm, __shfl_xor(sm, 32));

        if (__any(sm > m_r + 11.5f)) {       // defer-max (T13)
            float mnew = fmaxf(m_r, sm);
            float alpha = exp2_hw(m_r - mnew);
            l_r *= alpha;
            m_r = mnew;
            #pragma unroll
            for (int r = 0; r < 16; ++r) {
                float av = __shfl(alpha, (r & 3) + 8 * (r >> 2) + 4 * hi);
                #pragma unroll
                for (int dt = 0; dt < 4; ++dt) o_acc[dt][r] *= av;
            }
        }

        #pragma unroll
        for (int r = 0; r < 16; ++r) {
            s0[r] = exp2_hw(s0[r] - m_r);
            s1[r] = exp2_hw(s1[r] - m_r);
        }
        float st[8];
        #pragma unroll
        for (int i = 0; i < 8; ++i)
            st[i] = (s0[2 * i] + s0[2 * i + 1]) + (s1[2 * i] + s1[2 * i + 1]);
        l_r += ((st[0] + st[1]) + (st[2] + st[3])) + ((st[4] + st[5]) + (st[6] + st[7]));

        // ---- PV: redistribute P in-register, then mfma(P, V) ----
        #pragma unroll
        for (int t32 = 0; t32 < 2; ++t32) {
            const f32x16& s = t32 ? s1 : s0;
            unsigned int c0[4], c1[4];
            #pragma unroll
            for (int g = 0; g < 4; ++g) {
                c0[g] = cvtpk_bf16(s[4 * g],     s[4 * g + 1]);
                c1[g] = cvtpk_bf16(s[4 * g + 2], s[4 * g + 3]);
            }
            #pragma unroll
            for (int kt = 0; kt < 2; ++kt) {
                unsigned int sel0 = hi ? c0[2 * kt] : c0[2 * kt + 1];
                unsigned int sel1 = hi ? c1[2 * kt] : c1[2 * kt + 1];
                unsigned int o0 = (unsigned int)__shfl_xor((int)sel0, 32);
                unsigned int o1 = (unsigned int)__shfl_xor((int)sel1, 32);
                u32x4 uu;
                uu.x = hi ? o0 : c0[2 * kt];
                uu.y = hi ? o1 : c1[2 * kt];
                uu.z = hi ? c0[2 * kt + 1] : o0;
                uu.w = hi ? c1[2 * kt + 1] : o1;
                bf16x8 pf = __builtin_bit_cast(bf16x8, uu);
                __builtin_amdgcn_s_setprio(1);
                #pragma unroll
                for (int dt = 0; dt < 4; ++dt) {
                    bf16x8 vf = *(const bf16x8*)
                        &Vlds[bb][(dt * 32 + lc) * 64 + (((t32 * 4 + kt * 2 + hi) ^ kxor) * 8)];
                    o_acc[dt] = __builtin_amdgcn_mfma_f32_32x32x16_bf16(pf, vf, o_acc[dt], 0, 0, 0);
                }
                __builtin_amdgcn_s_setprio(0);
            }
        }
    }

    // ---- finalize: combine halves of l, normalize, write O ----
    float lt = l_r + __shfl_xor(l_r, 32);
    float inv = 1.0f / lt;
    #pragma unroll
    for (int r = 0; r < 16; ++r) {
        int qrow = (r & 3) + 8 * (r >> 2) + 4 * hi;
        float iv = __shfl(inv, qrow);
        #pragma unroll
        for (int dt = 0; dt < 4; ++dt)
            Og[base + (size_t)(q0w + qrow) * D_MODEL + h * D_HEAD + dt * 32 + lc] =
                f2bf(o_acc[dt][r] * iv);
    }
}

// ---------------------------------------------------------------------------
extern "C" void kernel_launch(void* const* d_in, const int* in_sizes, int n_in,
                              void* d_out, int out_size, void* d_ws, size_t ws_size,
                              hipStream_t stream)
{
    const float* queries = (const float*)d_in[0];
    const float* keys    = (const float*)d_in[1];
    const float* values  = (const float*)d_in[2];
    const float* Wq  = (const float*)d_in[3];
    const float* bq  = (const float*)d_in[4];
    const float* Wlk = (const float*)d_in[5];
    const float* blk = (const float*)d_in[6];
    const float* Wlv = (const float*)d_in[7];
    const float* blv = (const float*)d_in[8];
    const float* Wkr = (const float*)d_in[9];
    const float* bkr = (const float*)d_in[10];
    const float* Wvr = (const float*)d_in[11];
    const float* bvr = (const float*)d_in[12];
    const float* Wo  = (const float*)d_in[13];
    const float* bo  = (const float*)d_in[14];
    float* out = (float*)d_out;

    char* ws = (char*)d_ws;
    const size_t MB16 = (size_t)M_ROWS * D_MODEL * 2;       // 16 MB
    const size_t MB8  = (size_t)D_MODEL * D_MODEL * 2;      // 8 MB
    unsigned short* abf  = (unsigned short*)(ws);                 // reused; also ao
    unsigned short* q_bf = (unsigned short*)(ws + MB16);
    unsigned short* k_bf = (unsigned short*)(ws + 2 * MB16);
    unsigned short* v_t  = (unsigned short*)(ws + 3 * MB16);
    unsigned short* WqT  = (unsigned short*)(ws + 4 * MB16);
    unsigned short* WeTk = (unsigned short*)(ws + 4 * MB16 + MB8);
    unsigned short* WeTv = (unsigned short*)(ws + 4 * MB16 + 2 * MB8);
    unsigned short* WoT  = (unsigned short*)(ws + 4 * MB16 + 3 * MB8);
    float* beffk = (float*)(ws + 4 * MB16 + 4 * MB8);
    float* beffv = beffk + D_MODEL;

    const int nconv = (M_ROWS * D_MODEL) / 2048;   // 4096 blocks

    weff_t_kernel<<<dim3(32, 16, 2), 256, 0, stream>>>(
        Wlk, Wlv, Wkr, Wvr, blk, blv, bkr, bvr, WeTk, WeTv, beffk, beffv);
    transpose_w_kernel<<<dim3(32, 32, 2), 256, 0, stream>>>(Wq, Wo, WqT, WoT);

    conv_bf16_kernel<<<nconv, 256, 0, stream>>>(queries, abf);
    gemm_bt_kernel<0><<<dim3(16, 32), 256, 0, stream>>>(
        abf, WqT, bq, q_bf, M_ROWS, D_MODEL, D_MODEL, SCALE_Q);

    conv_bf16_kernel<<<nconv, 256, 0, stream>>>(keys, abf);
    gemm_bt_kernel<0><<<dim3(16, 32), 256, 0, stream>>>(
        abf, WeTk, beffk, k_bf, M_ROWS, D_MODEL, D_MODEL, 1.0f);

    conv_bf16_kernel<<<nconv, 256, 0, stream>>>(values, abf);
    gemm_bt_kernel<2><<<dim3(16, 32), 256, 0, stream>>>(
        abf, WeTv, beffv, v_t, M_ROWS, D_MODEL, D_MODEL, 1.0f);

    flash_kernel<<<512, 256, 0, stream>>>(q_bf, k_bf, v_t, abf);

    gemm_bt_kernel<1><<<dim3(16, 32), 256, 0, stream>>>(
        abf, WoT, bo, out, M_ROWS, D_MODEL, D_MODEL, 1.0f);
}